// Round 1
// baseline (461.876 us; speedup 1.0000x reference)
//
#include <hip/hip_runtime.h>

// Problem constants: B=4, C=19, H=512, W=1024
#define HW_PIX   524288              // H*W
#define NPIX     2097152             // B*H*W
#define NT4      524288              // NPIX/4 (one thread per float4 of pixels)
#define NCH      19
#define KSEL     1468006u            // int(0.7 * NPIX)
#define R1       16                  // replicated hist1 copies (atomic contention)
#define H1BINS   32768               // top-16-bit bins (sign=0 -> <32768)
#define H2BINS   65536               // low-16-bit bins
#define NBLK     2048                // NT4/256

// workspace layout (bytes); total ~10.9 MB
#define OFF_H1    (NPIX*4)                    //  8388608: R1*32768 u32 = 2 MB
#define OFF_COMB  (OFF_H1 + R1*H1BINS*4)      // 10485760: 32768 u32
#define OFF_H2    (OFF_COMB + H1BINS*4)       // 10616832: 65536 u32
#define OFF_PART  (OFF_H2 + H2BINS*4)         // 10878976: 2048 doubles
#define OFF_CTRL  (OFF_PART + NBLK*8)         // 10895360

struct Ctrl { unsigned bsel; unsigned c_above; unsigned T; unsigned r2; };

// ---------------------------------------------------------------------------
// K1: per-pixel loss (online log-softmax over C) + store + top16-bit histogram
// ---------------------------------------------------------------------------
__global__ __launch_bounds__(256) void k_loss_hist(
    const float* __restrict__ logits, const float* __restrict__ smooth,
    const float* __restrict__ wgt, float* __restrict__ loss,
    unsigned* __restrict__ hist1)
{
    int tid = blockIdx.x * 256 + threadIdx.x;     // 0..NT4-1
    int img = tid >> 17;                          // / 131072 float4 per image
    int rem = tid & 131071;
    const float4* L = (const float4*)logits + (size_t)img * (NCH * 131072) + rem;
    const float4* S = (const float4*)smooth + (size_t)img * (NCH * 131072) + rem;

    float4 xv = L[0];
    float4 sv = S[0];
    float wc = wgt[0];
    float m[4]  = {xv.x, xv.y, xv.z, xv.w};
    float s[4]  = {1.f, 1.f, 1.f, 1.f};
    float sw[4], swl[4];
    {
        float t0 = sv.x*wc, t1 = sv.y*wc, t2 = sv.z*wc, t3 = sv.w*wc;
        sw[0]=t0; sw[1]=t1; sw[2]=t2; sw[3]=t3;
        swl[0]=t0*xv.x; swl[1]=t1*xv.y; swl[2]=t2*xv.z; swl[3]=t3*xv.w;
    }
    #pragma unroll
    for (int c = 1; c < NCH; ++c) {
        xv = L[(size_t)c * 131072];
        sv = S[(size_t)c * 131072];
        wc = wgt[c];
        float xs[4] = {xv.x, xv.y, xv.z, xv.w};
        float ss[4] = {sv.x, sv.y, sv.z, sv.w};
        #pragma unroll
        for (int j = 0; j < 4; ++j) {
            float mn = fmaxf(m[j], xs[j]);
            s[j] = s[j]*__expf(m[j]-mn) + __expf(xs[j]-mn);
            m[j] = mn;
            float t = ss[j]*wc;
            sw[j]  += t;
            swl[j] += t*xs[j];
        }
    }
    float out[4];
    #pragma unroll
    for (int j = 0; j < 4; ++j) {
        float lse = m[j] + __logf(s[j]);
        out[j] = fmaxf(lse*sw[j] - swl[j], 0.0f);   // clamp fp-noise negatives
    }
    ((float4*)loss)[tid] = make_float4(out[0], out[1], out[2], out[3]);

    unsigned rep = (unsigned)(blockIdx.x & (R1-1)) * H1BINS;
    #pragma unroll
    for (int j = 0; j < 4; ++j)
        atomicAdd(&hist1[rep + (__float_as_uint(out[j]) >> 16)], 1u);
}

// ---------------------------------------------------------------------------
// K2: reduce histogram replicas
// ---------------------------------------------------------------------------
__global__ __launch_bounds__(256) void k_reduce_h1(
    const unsigned* __restrict__ h1, unsigned* __restrict__ comb)
{
    int i = blockIdx.x * 256 + threadIdx.x;       // 0..32767
    unsigned s = 0;
    #pragma unroll
    for (int r = 0; r < R1; ++r) s += h1[r * H1BINS + i];
    comb[i] = s;
}

// ---------------------------------------------------------------------------
// K3: find top-16-bit bin containing the k-th largest (suffix scan from top)
// ---------------------------------------------------------------------------
__global__ __launch_bounds__(256) void k_sel1(
    const unsigned* __restrict__ comb, Ctrl* __restrict__ ctrl)
{
    __shared__ unsigned cs[256];
    int t = threadIdx.x;
    unsigned sum = 0;
    for (int j = 0; j < 128; ++j) sum += comb[t*128 + j];
    cs[t] = sum; __syncthreads();
    for (int off = 1; off < 256; off <<= 1) {     // inclusive suffix scan
        unsigned v = (t + off < 256) ? cs[t + off] : 0u;
        __syncthreads();
        cs[t] += v;
        __syncthreads();
    }
    unsigned St = cs[t];
    unsigned Sn = (t < 255) ? cs[t + 1] : 0u;
    if (St >= KSEL && Sn < KSEL) {                // unique owner
        unsigned cum = Sn;
        for (int bin = t*128 + 127;; --bin) {
            unsigned c = comb[bin];
            if (cum + c >= KSEL) { ctrl->bsel = (unsigned)bin; ctrl->c_above = cum; break; }
            cum += c;
        }
    }
}

// ---------------------------------------------------------------------------
// K4: histogram low 16 bits of candidates in selected bin
// ---------------------------------------------------------------------------
__global__ __launch_bounds__(256) void k_hist2(
    const unsigned* __restrict__ lossbits, const Ctrl* __restrict__ ctrl,
    unsigned* __restrict__ h2)
{
    unsigned b = ctrl->bsel;
    int tid = blockIdx.x * 256 + threadIdx.x;
    uint4 v = ((const uint4*)lossbits)[tid];
    if ((v.x >> 16) == b) atomicAdd(&h2[v.x & 0xFFFFu], 1u);
    if ((v.y >> 16) == b) atomicAdd(&h2[v.y & 0xFFFFu], 1u);
    if ((v.z >> 16) == b) atomicAdd(&h2[v.z & 0xFFFFu], 1u);
    if ((v.w >> 16) == b) atomicAdd(&h2[v.w & 0xFFFFu], 1u);
}

// ---------------------------------------------------------------------------
// K5: finalize exact 32-bit threshold T and tie count r2
// ---------------------------------------------------------------------------
__global__ __launch_bounds__(256) void k_sel2(
    const unsigned* __restrict__ h2, Ctrl* __restrict__ ctrl)
{
    __shared__ unsigned cs[256];
    int t = threadIdx.x;
    unsigned r = KSEL - ctrl->c_above;            // needed from bin bsel (>=1)
    unsigned b = ctrl->bsel;
    unsigned sum = 0;
    for (int j = 0; j < 256; ++j) sum += h2[t*256 + j];
    cs[t] = sum; __syncthreads();
    for (int off = 1; off < 256; off <<= 1) {
        unsigned v = (t + off < 256) ? cs[t + off] : 0u;
        __syncthreads();
        cs[t] += v;
        __syncthreads();
    }
    unsigned St = cs[t];
    unsigned Sn = (t < 255) ? cs[t + 1] : 0u;
    if (St >= r && Sn < r) {
        unsigned cum = Sn;
        for (int bin = t*256 + 255;; --bin) {
            unsigned c = h2[bin];
            if (cum + c >= r) {
                ctrl->T  = (b << 16) | (unsigned)bin;
                ctrl->r2 = r - cum;               // # of threshold-valued elems included
                break;
            }
            cum += c;
        }
    }
}

// ---------------------------------------------------------------------------
// K6: sum of values strictly greater than T -> per-block double partials
// ---------------------------------------------------------------------------
__global__ __launch_bounds__(256) void k_sum(
    const unsigned* __restrict__ lossbits, const Ctrl* __restrict__ ctrl,
    double* __restrict__ partials)
{
    unsigned T = ctrl->T;
    int tid = blockIdx.x * 256 + threadIdx.x;
    uint4 v = ((const uint4*)lossbits)[tid];
    double acc = 0.0;
    if (v.x > T) acc += (double)__uint_as_float(v.x);
    if (v.y > T) acc += (double)__uint_as_float(v.y);
    if (v.z > T) acc += (double)__uint_as_float(v.z);
    if (v.w > T) acc += (double)__uint_as_float(v.w);
    #pragma unroll
    for (int off = 32; off > 0; off >>= 1) acc += __shfl_down(acc, off, 64);
    __shared__ double wsum[4];
    int lane = threadIdx.x & 63, wid = threadIdx.x >> 6;
    if (lane == 0) wsum[wid] = acc;
    __syncthreads();
    if (threadIdx.x == 0)
        partials[blockIdx.x] = wsum[0] + wsum[1] + wsum[2] + wsum[3];
}

// ---------------------------------------------------------------------------
// K7: final reduce + tie handling + mean
// ---------------------------------------------------------------------------
__global__ __launch_bounds__(256) void k_final(
    const double* __restrict__ partials, const Ctrl* __restrict__ ctrl,
    float* __restrict__ out)
{
    double acc = 0.0;
    for (int i = threadIdx.x; i < NBLK; i += 256) acc += partials[i];
    #pragma unroll
    for (int off = 32; off > 0; off >>= 1) acc += __shfl_down(acc, off, 64);
    __shared__ double wsum[4];
    int lane = threadIdx.x & 63, wid = threadIdx.x >> 6;
    if (lane == 0) wsum[wid] = acc;
    __syncthreads();
    if (threadIdx.x == 0) {
        double tot = wsum[0] + wsum[1] + wsum[2] + wsum[3];
        tot += (double)ctrl->r2 * (double)__uint_as_float(ctrl->T);
        out[0] = (float)(tot / (double)KSEL);
    }
}

// ---------------------------------------------------------------------------
extern "C" void kernel_launch(void* const* d_in, const int* in_sizes, int n_in,
                              void* d_out, int out_size, void* d_ws, size_t ws_size,
                              hipStream_t stream)
{
    const float* logits = (const float*)d_in[0];
    // d_in[1] (labels, int64) is unused by the reference
    const float* smooth = (const float*)d_in[2];
    const float* wgt    = (const float*)d_in[3];

    char* ws = (char*)d_ws;
    float*    loss     = (float*)ws;
    unsigned* h1       = (unsigned*)(ws + OFF_H1);
    unsigned* comb     = (unsigned*)(ws + OFF_COMB);
    unsigned* h2       = (unsigned*)(ws + OFF_H2);
    double*   partials = (double*)(ws + OFF_PART);
    Ctrl*     ctrl     = (Ctrl*)(ws + OFF_CTRL);

    hipMemsetAsync(h1, 0, R1 * H1BINS * 4, stream);
    hipMemsetAsync(h2, 0, H2BINS * 4, stream);

    k_loss_hist<<<NBLK, 256, 0, stream>>>(logits, smooth, wgt, loss, h1);
    k_reduce_h1<<<H1BINS/256, 256, 0, stream>>>(h1, comb);
    k_sel1<<<1, 256, 0, stream>>>(comb, ctrl);
    k_hist2<<<NBLK, 256, 0, stream>>>((const unsigned*)loss, ctrl, h2);
    k_sel2<<<1, 256, 0, stream>>>(h2, ctrl);
    k_sum<<<NBLK, 256, 0, stream>>>((const unsigned*)loss, ctrl, partials);
    k_final<<<1, 256, 0, stream>>>(partials, ctrl, (float*)d_out);
}

// Round 2
// 434.706 us; speedup vs baseline: 1.0625x; 1.0625x over previous
//
#include <hip/hip_runtime.h>

// Problem constants: B=4, C=19, H=512, W=1024
#define NPIX     2097152             // B*H*W
#define NT4      524288              // NPIX/4 (one thread per float4 of pixels)
#define NCH      19
#define KSEL     1468006u            // int(0.7 * NPIX)
#define R1       16                  // replicated hist1 copies
#define H1BINS   32768               // top-16-bit bins (sign=0 -> <32768)
#define H2BINS   65536               // low-16-bit bins
#define NBLK     2048                // NT4/256

// workspace layout (bytes); total ~10.9 MB. h1+h2 contiguous -> ONE memset.
#define OFF_H1    (NPIX*4)                    //  8388608: 16*32768 u32 = 2 MB
#define OFF_H2    (OFF_H1 + R1*H1BINS*4)      // 10485760: 65536 u32 = 256 KB
#define OFF_COMB  (OFF_H2 + H2BINS*4)         // 10747904: 32768 u32 = 128 KB
#define OFF_PART  (OFF_COMB + H1BINS*4)       // 10878976: 2048 doubles
#define OFF_CTRL  (OFF_PART + NBLK*8)         // 10895360

struct Ctrl { unsigned bsel; unsigned c_above; unsigned T; unsigned r2; };

// ---------------------------------------------------------------------------
// K1: per-pixel loss. All 19 logit float4s loaded upfront (MLP!), max in regs,
// single exp pass fused with streamed smooth loads. + top-16-bit histogram.
// ---------------------------------------------------------------------------
__global__ __launch_bounds__(256) void k_loss_hist(
    const float* __restrict__ logits, const float* __restrict__ smooth,
    const float* __restrict__ wgt, float* __restrict__ loss,
    unsigned* __restrict__ hist1)
{
    int tid = blockIdx.x * 256 + threadIdx.x;     // 0..NT4-1
    int img = tid >> 17;                          // / 131072 float4 per image
    int rem = tid & 131071;
    const float4* L = (const float4*)logits + (size_t)img * (NCH * 131072) + rem;
    const float4* S = (const float4*)smooth + (size_t)img * (NCH * 131072) + rem;

    // Phase A: all logits upfront -> 19 independent 16B loads in flight.
    float4 x[NCH];
    #pragma unroll
    for (int c = 0; c < NCH; ++c) x[c] = L[(size_t)c * 131072];

    // Phase B: register-resident max (no exp needed yet).
    float m0 = x[0].x, m1 = x[0].y, m2 = x[0].z, m3 = x[0].w;
    #pragma unroll
    for (int c = 1; c < NCH; ++c) {
        m0 = fmaxf(m0, x[c].x); m1 = fmaxf(m1, x[c].y);
        m2 = fmaxf(m2, x[c].z); m3 = fmaxf(m3, x[c].w);
    }

    // Phase C: one pass: sum of exp, and weighted-smooth accumulators,
    // streaming smooth (loads independent -> compiler hoists several ahead).
    float s0 = 0.f, s1 = 0.f, s2 = 0.f, s3 = 0.f;
    float sw0 = 0.f, sw1 = 0.f, sw2 = 0.f, sw3 = 0.f;
    float swl0 = 0.f, swl1 = 0.f, swl2 = 0.f, swl3 = 0.f;
    #pragma unroll
    for (int c = 0; c < NCH; ++c) {
        float4 sv = S[(size_t)c * 131072];
        float wc = wgt[c];
        s0 += __expf(x[c].x - m0); s1 += __expf(x[c].y - m1);
        s2 += __expf(x[c].z - m2); s3 += __expf(x[c].w - m3);
        float t0 = sv.x * wc, t1 = sv.y * wc, t2 = sv.z * wc, t3 = sv.w * wc;
        sw0 += t0; sw1 += t1; sw2 += t2; sw3 += t3;
        swl0 += t0 * x[c].x; swl1 += t1 * x[c].y;
        swl2 += t2 * x[c].z; swl3 += t3 * x[c].w;
    }

    float l0 = fmaxf((m0 + __logf(s0)) * sw0 - swl0, 0.f);
    float l1 = fmaxf((m1 + __logf(s1)) * sw1 - swl1, 0.f);
    float l2 = fmaxf((m2 + __logf(s2)) * sw2 - swl2, 0.f);
    float l3 = fmaxf((m3 + __logf(s3)) * sw3 - swl3, 0.f);

    ((float4*)loss)[tid] = make_float4(l0, l1, l2, l3);

    unsigned rep = (unsigned)(blockIdx.x & (R1 - 1)) * H1BINS;
    atomicAdd(&hist1[rep + (__float_as_uint(l0) >> 16)], 1u);
    atomicAdd(&hist1[rep + (__float_as_uint(l1) >> 16)], 1u);
    atomicAdd(&hist1[rep + (__float_as_uint(l2) >> 16)], 1u);
    atomicAdd(&hist1[rep + (__float_as_uint(l3) >> 16)], 1u);
}

// ---------------------------------------------------------------------------
// K2: reduce histogram replicas (grid-wide, coalesced)
// ---------------------------------------------------------------------------
__global__ __launch_bounds__(256) void k_reduce_h1(
    const unsigned* __restrict__ h1, unsigned* __restrict__ comb)
{
    int i = blockIdx.x * 256 + threadIdx.x;       // 0..32767
    unsigned s = 0;
    #pragma unroll
    for (int r = 0; r < R1; ++r) s += h1[r * H1BINS + i];
    comb[i] = s;
}

// ---------------------------------------------------------------------------
// K3: find top-16-bit bin containing the k-th largest.
// Two-level LDS suffix scan; NO serial dependent-load walk.
// ---------------------------------------------------------------------------
__global__ __launch_bounds__(256) void k_sel1(
    const unsigned* __restrict__ comb, Ctrl* __restrict__ ctrl)
{
    __shared__ unsigned cs[256];
    __shared__ unsigned d[128];
    __shared__ unsigned sh_t0, sh_base;
    int t = threadIdx.x;

    unsigned sum = 0;
    for (int j = 0; j < 128; ++j) sum += comb[t * 128 + j];
    cs[t] = sum; __syncthreads();
    for (int off = 1; off < 256; off <<= 1) {     // inclusive suffix scan
        unsigned v = (t + off < 256) ? cs[t + off] : 0u;
        __syncthreads();
        cs[t] += v;
        __syncthreads();
    }
    unsigned St = cs[t];
    unsigned Sn = (t < 255) ? cs[t + 1] : 0u;
    if (St >= KSEL && Sn < KSEL) { sh_t0 = (unsigned)t; sh_base = Sn; }
    __syncthreads();
    unsigned t0 = sh_t0, base = sh_base;

    if (t < 128) d[t] = comb[t0 * 128 + t];
    __syncthreads();
    for (int off = 1; off < 128; off <<= 1) {
        unsigned v = (t + off < 128) ? d[t + off] : 0u;
        __syncthreads();
        if (t < 128) d[t] += v;
        __syncthreads();
    }
    if (t < 128) {
        unsigned Su = d[t] + base;
        unsigned Sx = ((t < 127) ? d[t + 1] : 0u) + base;  // strictly-above count
        if (Su >= KSEL && Sx < KSEL) {
            ctrl->bsel = t0 * 128 + (unsigned)t;
            ctrl->c_above = Sx;
        }
    }
}

// ---------------------------------------------------------------------------
// K4: histogram low 16 bits of candidates in selected bin
// ---------------------------------------------------------------------------
__global__ __launch_bounds__(256) void k_hist2(
    const unsigned* __restrict__ lossbits, const Ctrl* __restrict__ ctrl,
    unsigned* __restrict__ h2)
{
    unsigned b = ctrl->bsel;
    int tid = blockIdx.x * 256 + threadIdx.x;
    uint4 v = ((const uint4*)lossbits)[tid];
    if ((v.x >> 16) == b) atomicAdd(&h2[v.x & 0xFFFFu], 1u);
    if ((v.y >> 16) == b) atomicAdd(&h2[v.y & 0xFFFFu], 1u);
    if ((v.z >> 16) == b) atomicAdd(&h2[v.z & 0xFFFFu], 1u);
    if ((v.w >> 16) == b) atomicAdd(&h2[v.w & 0xFFFFu], 1u);
}

// ---------------------------------------------------------------------------
// K5: exact 32-bit threshold T and tie count r2 (parallel scan, no walk)
// ---------------------------------------------------------------------------
__global__ __launch_bounds__(256) void k_sel2(
    const unsigned* __restrict__ h2, Ctrl* __restrict__ ctrl)
{
    __shared__ unsigned cs[256];
    __shared__ unsigned d[256];
    __shared__ unsigned sh_t0, sh_base;
    int t = threadIdx.x;
    unsigned r = KSEL - ctrl->c_above;            // needed from bin bsel (>=1)
    unsigned b = ctrl->bsel;

    unsigned sum = 0;
    for (int j = 0; j < 256; ++j) sum += h2[t * 256 + j];
    cs[t] = sum; __syncthreads();
    for (int off = 1; off < 256; off <<= 1) {
        unsigned v = (t + off < 256) ? cs[t + off] : 0u;
        __syncthreads();
        cs[t] += v;
        __syncthreads();
    }
    unsigned St = cs[t];
    unsigned Sn = (t < 255) ? cs[t + 1] : 0u;
    if (St >= r && Sn < r) { sh_t0 = (unsigned)t; sh_base = Sn; }
    __syncthreads();
    unsigned t0 = sh_t0, base = sh_base;

    d[t] = h2[t0 * 256 + t];
    __syncthreads();
    for (int off = 1; off < 256; off <<= 1) {
        unsigned v = (t + off < 256) ? d[t + off] : 0u;
        __syncthreads();
        d[t] += v;
        __syncthreads();
    }
    {
        unsigned Su = d[t] + base;
        unsigned Sx = ((t < 255) ? d[t + 1] : 0u) + base;
        if (Su >= r && Sx < r) {
            ctrl->T  = (b << 16) | (unsigned)t0 * 256 | (unsigned)t;
            ctrl->r2 = r - Sx;
        }
    }
}

// ---------------------------------------------------------------------------
// K6: sum of values strictly greater than T -> per-block double partials
// ---------------------------------------------------------------------------
__global__ __launch_bounds__(256) void k_sum(
    const unsigned* __restrict__ lossbits, const Ctrl* __restrict__ ctrl,
    double* __restrict__ partials)
{
    unsigned T = ctrl->T;
    int tid = blockIdx.x * 256 + threadIdx.x;
    uint4 v = ((const uint4*)lossbits)[tid];
    double acc = 0.0;
    if (v.x > T) acc += (double)__uint_as_float(v.x);
    if (v.y > T) acc += (double)__uint_as_float(v.y);
    if (v.z > T) acc += (double)__uint_as_float(v.z);
    if (v.w > T) acc += (double)__uint_as_float(v.w);
    #pragma unroll
    for (int off = 32; off > 0; off >>= 1) acc += __shfl_down(acc, off, 64);
    __shared__ double wsum[4];
    int lane = threadIdx.x & 63, wid = threadIdx.x >> 6;
    if (lane == 0) wsum[wid] = acc;
    __syncthreads();
    if (threadIdx.x == 0)
        partials[blockIdx.x] = wsum[0] + wsum[1] + wsum[2] + wsum[3];
}

// ---------------------------------------------------------------------------
// K7: final reduce + tie handling + mean
// ---------------------------------------------------------------------------
__global__ __launch_bounds__(256) void k_final(
    const double* __restrict__ partials, const Ctrl* __restrict__ ctrl,
    float* __restrict__ out)
{
    double acc = 0.0;
    for (int i = threadIdx.x; i < NBLK; i += 256) acc += partials[i];
    #pragma unroll
    for (int off = 32; off > 0; off >>= 1) acc += __shfl_down(acc, off, 64);
    __shared__ double wsum[4];
    int lane = threadIdx.x & 63, wid = threadIdx.x >> 6;
    if (lane == 0) wsum[wid] = acc;
    __syncthreads();
    if (threadIdx.x == 0) {
        double tot = wsum[0] + wsum[1] + wsum[2] + wsum[3];
        tot += (double)ctrl->r2 * (double)__uint_as_float(ctrl->T);
        out[0] = (float)(tot / (double)KSEL);
    }
}

// ---------------------------------------------------------------------------
extern "C" void kernel_launch(void* const* d_in, const int* in_sizes, int n_in,
                              void* d_out, int out_size, void* d_ws, size_t ws_size,
                              hipStream_t stream)
{
    const float* logits = (const float*)d_in[0];
    // d_in[1] (labels, int64) is unused by the reference
    const float* smooth = (const float*)d_in[2];
    const float* wgt    = (const float*)d_in[3];

    char* ws = (char*)d_ws;
    float*    loss     = (float*)ws;
    unsigned* h1       = (unsigned*)(ws + OFF_H1);
    unsigned* h2       = (unsigned*)(ws + OFF_H2);
    unsigned* comb     = (unsigned*)(ws + OFF_COMB);
    double*   partials = (double*)(ws + OFF_PART);
    Ctrl*     ctrl     = (Ctrl*)(ws + OFF_CTRL);

    // h1 and h2 are contiguous: single memset
    hipMemsetAsync(h1, 0, (R1 * H1BINS + H2BINS) * 4, stream);

    k_loss_hist<<<NBLK, 256, 0, stream>>>(logits, smooth, wgt, loss, h1);
    k_reduce_h1<<<H1BINS / 256, 256, 0, stream>>>(h1, comb);
    k_sel1<<<1, 256, 0, stream>>>(comb, ctrl);
    k_hist2<<<NBLK, 256, 0, stream>>>((const unsigned*)loss, ctrl, h2);
    k_sel2<<<1, 256, 0, stream>>>(h2, ctrl);
    k_sum<<<NBLK, 256, 0, stream>>>((const unsigned*)loss, ctrl, partials);
    k_final<<<1, 256, 0, stream>>>(partials, ctrl, (float*)d_out);
}

// Round 3
// 375.342 us; speedup vs baseline: 1.2305x; 1.1582x over previous
//
#include <hip/hip_runtime.h>

// Problem constants: B=4, C=19, H=512, W=1024
#define NPIX     2097152             // B*H*W
#define NT4      524288              // NPIX/4
#define NCH      19
#define KSEL     1468006u            // int(0.7 * NPIX)
#define NBLK     2048                // NT4/256 (K1, k_sum grids)
#define H1B      4096                // level-1 bins (bits 31..20)
#define H23B     1024                // level-2/3 bins (10 bits)
#define NHB      128                 // histogram blocks (rows)

// workspace layout (bytes); total ~10.5 MB — NO memset needed (no global atomics)
#define OFF_ROWS  (NPIX*4)                   //  8388608: 128*4096 u32 = 2 MB (reused lvl2/3)
#define OFF_COMB1 (OFF_ROWS + NHB*H1B*4)     // 10485760: 4096 u32
#define OFF_COMB2 (OFF_COMB1 + H1B*4)        // 10502144: 1024 u32 (reused lvl3)
#define OFF_PART  (OFF_COMB2 + H23B*4)       // 10506240: 2048 doubles
#define OFF_CTRL  (OFF_PART + NBLK*8)        // 10522624

struct Ctrl { unsigned p1, n1, p2, n2, T, r2; };

// ---------------------------------------------------------------------------
// K1: per-pixel loss, online log-softmax, depth-4 ping-pong prefetch.
// NO atomics, NO histogram — pure coalesced streaming.
// ---------------------------------------------------------------------------
__global__ __launch_bounds__(256) void k_loss(
    const float* __restrict__ logits, const float* __restrict__ smooth,
    const float* __restrict__ wgt, float* __restrict__ loss)
{
    int tid = blockIdx.x * 256 + threadIdx.x;     // 0..NT4-1
    int img = tid >> 17;                          // 131072 float4 per image
    int rem = tid & 131071;
    const float4* L = (const float4*)logits + (size_t)img * (NCH * 131072) + rem;
    const float4* S = (const float4*)smooth + (size_t)img * (NCH * 131072) + rem;

    // depth-4 prefetch ring: 8 independent 16B loads in flight per wave
    float4 xb[4], sb[4];
    #pragma unroll
    for (int i = 0; i < 4; ++i) {
        xb[i] = L[(size_t)i * 131072];
        sb[i] = S[(size_t)i * 131072];
    }

    float m0 = -3.4e38f, m1 = -3.4e38f, m2 = -3.4e38f, m3 = -3.4e38f;
    float s0 = 0.f, s1 = 0.f, s2 = 0.f, s3 = 0.f;
    float sw0 = 0.f, sw1 = 0.f, sw2 = 0.f, sw3 = 0.f;
    float swl0 = 0.f, swl1 = 0.f, swl2 = 0.f, swl3 = 0.f;

    #pragma unroll
    for (int c = 0; c < NCH; ++c) {
        float4 xv = xb[c & 3];
        float4 sv = sb[c & 3];
        if (c + 4 < NCH) {                        // issue next loads early
            xb[c & 3] = L[(size_t)(c + 4) * 131072];
            sb[c & 3] = S[(size_t)(c + 4) * 131072];
        }
        float wc = wgt[c];

        float n0 = fmaxf(m0, xv.x), n1 = fmaxf(m1, xv.y);
        float n2 = fmaxf(m2, xv.z), n3 = fmaxf(m3, xv.w);
        s0 = s0 * __expf(m0 - n0) + __expf(xv.x - n0);
        s1 = s1 * __expf(m1 - n1) + __expf(xv.y - n1);
        s2 = s2 * __expf(m2 - n2) + __expf(xv.z - n2);
        s3 = s3 * __expf(m3 - n3) + __expf(xv.w - n3);
        m0 = n0; m1 = n1; m2 = n2; m3 = n3;

        float t0 = sv.x * wc, t1 = sv.y * wc, t2 = sv.z * wc, t3 = sv.w * wc;
        sw0 += t0; sw1 += t1; sw2 += t2; sw3 += t3;
        swl0 += t0 * xv.x; swl1 += t1 * xv.y;
        swl2 += t2 * xv.z; swl3 += t3 * xv.w;
    }

    float l0 = fmaxf((m0 + __logf(s0)) * sw0 - swl0, 0.f);
    float l1 = fmaxf((m1 + __logf(s1)) * sw1 - swl1, 0.f);
    float l2 = fmaxf((m2 + __logf(s2)) * sw2 - swl2, 0.f);
    float l3 = fmaxf((m3 + __logf(s3)) * sw3 - swl3, 0.f);

    ((float4*)loss)[tid] = make_float4(l0, l1, l2, l3);
}

// ---------------------------------------------------------------------------
// H1: per-block LDS histogram of top-12 bits -> non-atomic row write
// ---------------------------------------------------------------------------
__global__ __launch_bounds__(256) void k_hist1(
    const uint4* __restrict__ lossbits, unsigned* __restrict__ rows)
{
    __shared__ unsigned h[H1B];
    int t = threadIdx.x;
    #pragma unroll
    for (int j = t; j < H1B; j += 256) h[j] = 0;
    __syncthreads();
    int base = blockIdx.x * (NT4 / NHB);          // 4096 uint4 per block
    for (int i = t; i < NT4 / NHB; i += 256) {
        uint4 v = lossbits[base + i];
        atomicAdd(&h[v.x >> 20], 1u);
        atomicAdd(&h[v.y >> 20], 1u);
        atomicAdd(&h[v.z >> 20], 1u);
        atomicAdd(&h[v.w >> 20], 1u);
    }
    __syncthreads();
    for (int j = t; j < H1B; j += 256)
        rows[blockIdx.x * H1B + j] = h[j];
}

// ---------------------------------------------------------------------------
// H2/H3: LDS histogram of next 10 bits among candidates matching prefix
// lvl=0: match bits31..20==p1, bin = bits19..10 ; lvl=1: match bits31..10==p2, bin = bits9..0
// ---------------------------------------------------------------------------
__global__ __launch_bounds__(256) void k_histr(
    const uint4* __restrict__ lossbits, const Ctrl* __restrict__ ctrl,
    unsigned* __restrict__ rows, int lvl)
{
    __shared__ unsigned h[H23B];
    unsigned pref = (lvl == 0) ? ctrl->p1 : ctrl->p2;
    int ms = (lvl == 0) ? 20 : 10;                // match shift
    int bs = (lvl == 0) ? 10 : 0;                 // bin shift
    int t = threadIdx.x;
    #pragma unroll
    for (int j = t; j < H23B; j += 256) h[j] = 0;
    __syncthreads();
    int base = blockIdx.x * (NT4 / NHB);
    for (int i = t; i < NT4 / NHB; i += 256) {
        uint4 v = lossbits[base + i];
        if ((v.x >> ms) == pref) atomicAdd(&h[(v.x >> bs) & 1023u], 1u);
        if ((v.y >> ms) == pref) atomicAdd(&h[(v.y >> bs) & 1023u], 1u);
        if ((v.z >> ms) == pref) atomicAdd(&h[(v.z >> bs) & 1023u], 1u);
        if ((v.w >> ms) == pref) atomicAdd(&h[(v.w >> bs) & 1023u], 1u);
    }
    __syncthreads();
    for (int j = t; j < H23B; j += 256)
        rows[blockIdx.x * H23B + j] = h[j];
}

// ---------------------------------------------------------------------------
// R: column-reduce NHB rows -> comb (coalesced, non-atomic)
// ---------------------------------------------------------------------------
__global__ __launch_bounds__(256) void k_reduce(
    const unsigned* __restrict__ rows, unsigned* __restrict__ comb, int nbins)
{
    int i = blockIdx.x * 256 + threadIdx.x;
    unsigned s = 0;
    for (int b = 0; b < NHB; ++b) s += rows[b * nbins + i];
    comb[i] = s;
}

// ---------------------------------------------------------------------------
// S1: single-block suffix-scan over 4096 bins -> p1 (12-bit prefix), n1
// ---------------------------------------------------------------------------
__global__ __launch_bounds__(256) void k_sel1(
    const unsigned* __restrict__ comb, Ctrl* __restrict__ ctrl)
{
    __shared__ unsigned bins[H1B];
    __shared__ unsigned cs[256];
    __shared__ unsigned sh_t0, sh_base;
    int t = threadIdx.x;
    for (int j = t; j < H1B; j += 256) bins[j] = comb[j];
    __syncthreads();
    unsigned sum = 0;
    #pragma unroll
    for (int j = 0; j < 16; ++j) sum += bins[t * 16 + j];
    cs[t] = sum; __syncthreads();
    for (int off = 1; off < 256; off <<= 1) {     // inclusive suffix scan
        unsigned v = (t + off < 256) ? cs[t + off] : 0u;
        __syncthreads();
        cs[t] += v;
        __syncthreads();
    }
    unsigned St = cs[t], Sn = (t < 255) ? cs[t + 1] : 0u;
    if (St >= KSEL && Sn < KSEL) { sh_t0 = (unsigned)t; sh_base = Sn; }
    __syncthreads();
    if (t == 0) {
        unsigned cum = sh_base;
        for (int b = (int)sh_t0 * 16 + 15;; --b) {
            unsigned c = bins[b];
            if (cum + c >= KSEL) { ctrl->p1 = (unsigned)b; ctrl->n1 = KSEL - cum; break; }
            cum += c;
        }
    }
}

// ---------------------------------------------------------------------------
// S2/S3: single-block suffix-scan over 1024 bins; extend prefix by 10 bits
// ---------------------------------------------------------------------------
__global__ __launch_bounds__(256) void k_selr(
    const unsigned* __restrict__ comb, Ctrl* __restrict__ ctrl, int lvl)
{
    __shared__ unsigned bins[H23B];
    __shared__ unsigned cs[256];
    __shared__ unsigned sh_t0, sh_base;
    int t = threadIdx.x;
    unsigned need = (lvl == 0) ? ctrl->n1 : ctrl->n2;
    unsigned pref = (lvl == 0) ? ctrl->p1 : ctrl->p2;
    for (int j = t; j < H23B; j += 256) bins[j] = comb[j];
    __syncthreads();
    unsigned sum = bins[t*4] + bins[t*4+1] + bins[t*4+2] + bins[t*4+3];
    cs[t] = sum; __syncthreads();
    for (int off = 1; off < 256; off <<= 1) {
        unsigned v = (t + off < 256) ? cs[t + off] : 0u;
        __syncthreads();
        cs[t] += v;
        __syncthreads();
    }
    unsigned St = cs[t], Sn = (t < 255) ? cs[t + 1] : 0u;
    if (St >= need && Sn < need) { sh_t0 = (unsigned)t; sh_base = Sn; }
    __syncthreads();
    if (t == 0) {
        unsigned cum = sh_base;
        for (int b = (int)sh_t0 * 4 + 3;; --b) {
            unsigned c = bins[b];
            if (cum + c >= need) {
                if (lvl == 0) { ctrl->p2 = (pref << 10) | (unsigned)b; ctrl->n2 = need - cum; }
                else          { ctrl->T  = (pref << 10) | (unsigned)b; ctrl->r2 = need - cum; }
                break;
            }
            cum += c;
        }
    }
}

// ---------------------------------------------------------------------------
// K6: sum of values strictly greater than T -> per-block double partials
// ---------------------------------------------------------------------------
__global__ __launch_bounds__(256) void k_sum(
    const uint4* __restrict__ lossbits, const Ctrl* __restrict__ ctrl,
    double* __restrict__ partials)
{
    unsigned T = ctrl->T;
    int tid = blockIdx.x * 256 + threadIdx.x;
    uint4 v = lossbits[tid];
    double acc = 0.0;
    if (v.x > T) acc += (double)__uint_as_float(v.x);
    if (v.y > T) acc += (double)__uint_as_float(v.y);
    if (v.z > T) acc += (double)__uint_as_float(v.z);
    if (v.w > T) acc += (double)__uint_as_float(v.w);
    #pragma unroll
    for (int off = 32; off > 0; off >>= 1) acc += __shfl_down(acc, off, 64);
    __shared__ double wsum[4];
    int lane = threadIdx.x & 63, wid = threadIdx.x >> 6;
    if (lane == 0) wsum[wid] = acc;
    __syncthreads();
    if (threadIdx.x == 0)
        partials[blockIdx.x] = wsum[0] + wsum[1] + wsum[2] + wsum[3];
}

// ---------------------------------------------------------------------------
// K7: final reduce + tie handling + mean
// ---------------------------------------------------------------------------
__global__ __launch_bounds__(256) void k_final(
    const double* __restrict__ partials, const Ctrl* __restrict__ ctrl,
    float* __restrict__ out)
{
    double acc = 0.0;
    for (int i = threadIdx.x; i < NBLK; i += 256) acc += partials[i];
    #pragma unroll
    for (int off = 32; off > 0; off >>= 1) acc += __shfl_down(acc, off, 64);
    __shared__ double wsum[4];
    int lane = threadIdx.x & 63, wid = threadIdx.x >> 6;
    if (lane == 0) wsum[wid] = acc;
    __syncthreads();
    if (threadIdx.x == 0) {
        double tot = wsum[0] + wsum[1] + wsum[2] + wsum[3];
        tot += (double)ctrl->r2 * (double)__uint_as_float(ctrl->T);
        out[0] = (float)(tot / (double)KSEL);
    }
}

// ---------------------------------------------------------------------------
extern "C" void kernel_launch(void* const* d_in, const int* in_sizes, int n_in,
                              void* d_out, int out_size, void* d_ws, size_t ws_size,
                              hipStream_t stream)
{
    const float* logits = (const float*)d_in[0];
    // d_in[1] (labels, int64) is unused by the reference
    const float* smooth = (const float*)d_in[2];
    const float* wgt    = (const float*)d_in[3];

    char* ws = (char*)d_ws;
    float*    loss     = (float*)ws;
    unsigned* rows     = (unsigned*)(ws + OFF_ROWS);
    unsigned* comb1    = (unsigned*)(ws + OFF_COMB1);
    unsigned* comb2    = (unsigned*)(ws + OFF_COMB2);
    double*   partials = (double*)(ws + OFF_PART);
    Ctrl*     ctrl     = (Ctrl*)(ws + OFF_CTRL);
    const uint4* lb    = (const uint4*)loss;

    k_loss  <<<NBLK, 256, 0, stream>>>(logits, smooth, wgt, loss);
    k_hist1 <<<NHB, 256, 0, stream>>>(lb, rows);
    k_reduce<<<H1B / 256, 256, 0, stream>>>(rows, comb1, H1B);
    k_sel1  <<<1, 256, 0, stream>>>(comb1, ctrl);
    k_histr <<<NHB, 256, 0, stream>>>(lb, ctrl, rows, 0);
    k_reduce<<<H23B / 256, 256, 0, stream>>>(rows, comb2, H23B);
    k_selr  <<<1, 256, 0, stream>>>(comb2, ctrl, 0);
    k_histr <<<NHB, 256, 0, stream>>>(lb, ctrl, rows, 1);
    k_reduce<<<H23B / 256, 256, 0, stream>>>(rows, comb2, H23B);
    k_selr  <<<1, 256, 0, stream>>>(comb2, ctrl, 1);
    k_sum   <<<NBLK, 256, 0, stream>>>(lb, ctrl, partials);
    k_final <<<1, 256, 0, stream>>>(partials, ctrl, (float*)d_out);
}